// Round 1
// baseline (161.316 us; speedup 1.0000x reference)
//
#include <hip/hip_runtime.h>

#define NQ   6
#define DIM  64      // 2^NQ
#define NMOD 32
#define NCL  32
#define BATCH 2048
#define NCLS 150
#define KF   192     // NMOD*NQ
#define NROWS (BATCH*NMOD)   // 65536

// ---------------------------------------------------------------------------
// ws layout (float offsets):
//   cstab : NMOD*NCL*NQ*2            = 12288     (cos/sin of 0.5*qw)
//   U2    : NMOD*DIM*DIM*2           = 262144    (per-module unitary, float2)
//   camps : NROWS*NQ*2               = 786432    (cos/sin of 0.5*angle)
//   outs  : BATCH*KF                 = 393216    (per-module Z expectations)
#define OFF_CSTAB 0
#define OFF_U2    12288
#define OFF_CAMPS 274432
#define OFF_OUTS  1060864

// ---------------------------------------------------------------------------
// A0: cos/sin table for circuit weights
__global__ __launch_bounds__(256) void k_cstab(const float* __restrict__ qw,
                                               float* __restrict__ cstab) {
    int i = blockIdx.x * 256 + threadIdx.x;
    if (i < NMOD * NCL * NQ) {
        float s, c;
        sincosf(0.5f * qw[i], &s, &c);
        cstab[2 * i + 0] = c;
        cstab[2 * i + 1] = s;
    }
}

// ---------------------------------------------------------------------------
// K0: angles = parts @ Wp^T + bp, then store (cos(a/2), sin(a/2)).
// features viewed as (NROWS, 64) — rows are contiguous. 32 rows per block.
__global__ __launch_bounds__(192) void k_angles(const float* __restrict__ features,
                                                const float* __restrict__ Wp,
                                                const float* __restrict__ bp,
                                                float* __restrict__ camps) {
    __shared__ float ldsA[64 * 33];   // [d][r], padded stride 33
    __shared__ float ldsW[NQ * 64];
    int tid = threadIdx.x;
    int rowbase = blockIdx.x * 32;
    const float* src = features + (size_t)rowbase * 64;
    for (int idx = tid; idx < 32 * 64; idx += 192) {
        int r = idx >> 6, d = idx & 63;
        ldsA[d * 33 + r] = src[idx];
    }
    for (int idx = tid; idx < NQ * 64; idx += 192) ldsW[idx] = Wp[idx];
    __syncthreads();

    int q = tid >> 5;        // 0..5
    int r = tid & 31;        // 0..31
    float acc = 0.f;
#pragma unroll
    for (int d = 0; d < 64; ++d) acc += ldsA[d * 33 + r] * ldsW[q * 64 + d];
    float half = 0.5f * (acc + bp[q]);
    float s, c;
    sincosf(half, &s, &c);
    int row = rowbase + r;
    camps[(row * NQ + q) * 2 + 0] = c;
    camps[(row * NQ + q) * 2 + 1] = s;
}

// ---------------------------------------------------------------------------
// A: build U_p columns. One wave per (p, col); lane i holds amplitude i.
// RX(q):   a' = c*a - i*s*a_partner   (partner = lane ^ (1<<(5-q)))
// CNOT(q->q+1): lanes with ctrl bit set take partner (lane ^ tgt_mask) value.
__global__ __launch_bounds__(256) void k_unitary(const float* __restrict__ cstab,
                                                 float* __restrict__ U2f) {
    int tid = threadIdx.x;
    int lane = tid & 63;
    int w = tid >> 6;                  // wave in block (0..3)
    int p = blockIdx.x >> 4;           // 0..31
    int col = ((blockIdx.x & 15) << 2) + w;   // 0..63

    float re = (lane == col) ? 1.f : 0.f;
    float im = 0.f;
    const float* cs = cstab + p * NCL * NQ * 2;

    for (int layer = 0; layer < NCL; ++layer) {
        const float* lw = cs + layer * NQ * 2;
#pragma unroll
        for (int q = 0; q < NQ; ++q) {
            float c = lw[2 * q], s = lw[2 * q + 1];
            int mask = 1 << (5 - q);
            float pre = __shfl_xor(re, mask, 64);
            float pim = __shfl_xor(im, mask, 64);
            float nre = fmaf(c, re, s * pim);
            float nim = fmaf(c, im, -s * pre);
            re = nre;
            im = nim;
        }
#pragma unroll
        for (int q = 0; q < NQ; ++q) {
            int cmask = 1 << (5 - q);
            int tmask = 1 << (5 - ((q + 1) % 6));
            float pre = __shfl_xor(re, tmask, 64);
            float pim = __shfl_xor(im, tmask, 64);
            bool ctrl = (lane & cmask) != 0;
            re = ctrl ? pre : re;
            im = ctrl ? pim : im;
        }
    }
    float2* dst = (float2*)U2f;
    dst[p * (DIM * DIM) + col * DIM + lane] = make_float2(re, im);
}

// ---------------------------------------------------------------------------
// B: per (p, 8 batch elems) wave: psi0 -> y = U_p psi0 -> |y|^2 -> WHT -> z_q
__global__ __launch_bounds__(256) void k_circuit(const float* __restrict__ camps,
                                                 const float* __restrict__ U2f,
                                                 float* __restrict__ outs) {
    __shared__ float psi[4][64][8];    // [wave][col][bi]
    int tid = threadIdx.x;
    int lane = tid & 63;
    int w = tid >> 6;
    int p = blockIdx.x & 31;
    int btile = blockIdx.x >> 5;       // 0..63
    int b0 = btile * 32 + w * 8;

    // psi0 for this lane's basis index, for 8 batch elems
    float pv[8];
#pragma unroll
    for (int bi = 0; bi < 8; ++bi) {
        int row = (b0 + bi) * NMOD + p;
        const float* ca = camps + row * NQ * 2;
        float v = 1.f;
#pragma unroll
        for (int q = 0; q < NQ; ++q) {
            float c = ca[2 * q], s = ca[2 * q + 1];
            v *= ((lane >> (5 - q)) & 1) ? s : c;
        }
        pv[bi] = v;
    }
    *(float4*)&psi[w][lane][0] = make_float4(pv[0], pv[1], pv[2], pv[3]);
    *(float4*)&psi[w][lane][4] = make_float4(pv[4], pv[5], pv[6], pv[7]);
    __syncthreads();

    const float2* U = (const float2*)U2f + p * (DIM * DIM);
    float yre[8], yim[8];
#pragma unroll
    for (int bi = 0; bi < 8; ++bi) { yre[bi] = 0.f; yim[bi] = 0.f; }

#pragma unroll 8
    for (int col = 0; col < 64; ++col) {
        float2 u = U[col * 64 + lane];
        float pc[8];
        *(float4*)&pc[0] = *(const float4*)&psi[w][col][0];
        *(float4*)&pc[4] = *(const float4*)&psi[w][col][4];
#pragma unroll
        for (int bi = 0; bi < 8; ++bi) {
            yre[bi] = fmaf(u.x, pc[bi], yre[bi]);
            yim[bi] = fmaf(u.y, pc[bi], yim[bi]);
        }
    }

    // measurement: 6-step Walsh-Hadamard butterfly over lanes;
    // lane m ends with sum_l (-1)^{popcount(l&m)} prob_l; z_q at m = 1<<(5-q)
    float sgn[6];
#pragma unroll
    for (int k = 0; k < 6; ++k) sgn[k] = ((lane >> k) & 1) ? -1.f : 1.f;

#pragma unroll
    for (int bi = 0; bi < 8; ++bi) {
        float v = yre[bi] * yre[bi] + yim[bi] * yim[bi];
#pragma unroll
        for (int k = 0; k < 6; ++k) {
            float t = __shfl_xor(v, 1 << k, 64);
            v = fmaf(sgn[k], v, t);
        }
        if (lane != 0 && (lane & (lane - 1)) == 0) {
            int bpos = __ffs(lane) - 1;
            int q = 5 - bpos;
            outs[(b0 + bi) * KF + p * NQ + q] = v;
        }
    }
}

// ---------------------------------------------------------------------------
// C: out = outs @ Wf^T + bf.  Lane->b (coalesced via L1), c wave-uniform.
__global__ __launch_bounds__(256) void k_final(const float* __restrict__ outs,
                                               const float* __restrict__ Wf,
                                               const float* __restrict__ bf,
                                               float* __restrict__ out) {
    int tid = threadIdx.x;
    int b = blockIdx.x * 64 + (tid & 63);
    int c = blockIdx.y * 4 + (tid >> 6);
    if (c >= NCLS) return;
    float acc = bf[c];
    const float* orow = outs + b * KF;
    const float* wrow = Wf + c * KF;
#pragma unroll
    for (int k = 0; k < KF; k += 4) {
        float4 o = *(const float4*)&orow[k];
        float4 wv = *(const float4*)&wrow[k];
        acc = fmaf(o.x, wv.x, acc);
        acc = fmaf(o.y, wv.y, acc);
        acc = fmaf(o.z, wv.z, acc);
        acc = fmaf(o.w, wv.w, acc);
    }
    out[b * NCLS + c] = acc;
}

// ---------------------------------------------------------------------------
extern "C" void kernel_launch(void* const* d_in, const int* in_sizes, int n_in,
                              void* d_out, int out_size, void* d_ws, size_t ws_size,
                              hipStream_t stream) {
    const float* features = (const float*)d_in[0];
    const float* Wp       = (const float*)d_in[1];
    const float* bp       = (const float*)d_in[2];
    const float* qw       = (const float*)d_in[3];
    const float* Wf       = (const float*)d_in[4];
    const float* bf       = (const float*)d_in[5];
    float* out = (float*)d_out;
    float* ws  = (float*)d_ws;

    float* cstab = ws + OFF_CSTAB;
    float* U2    = ws + OFF_U2;
    float* camps = ws + OFF_CAMPS;
    float* outsb = ws + OFF_OUTS;

    k_cstab<<<(NMOD * NCL * NQ + 255) / 256, 256, 0, stream>>>(qw, cstab);
    k_angles<<<NROWS / 32, 192, 0, stream>>>(features, Wp, bp, camps);
    k_unitary<<<NMOD * 16, 256, 0, stream>>>(cstab, U2);
    k_circuit<<<NMOD * (BATCH / 32), 256, 0, stream>>>(camps, U2, outsb);
    k_final<<<dim3(BATCH / 64, (NCLS + 3) / 4), 256, 0, stream>>>(outsb, Wf, bf, out);
}